// Round 6
// baseline (29.849 us; speedup 1.0000x reference)
//
#include <hip/hip_runtime.h>

#define T_LEN  512
#define K_LEN  64
#define NFILT  32
#define NBATCH 64
#define SQRT_LOG2E 1.2011224087864498f
#define LN2        0.6931471805599453f

// result[lane] = src[lane-1], lane0 -> 0 (DPP wave_shr:1, bound_ctrl=1)
static __device__ __forceinline__ float wave_shr1(float x) {
    int r = __builtin_amdgcn_update_dpp(0, __builtin_bit_cast(int, x),
                                        0x138, 0xF, 0xF, true);
    return __builtin_bit_cast(float, r);
}

template <int N>
static __device__ __forceinline__ float row_ror(float x) {
    int r = __builtin_amdgcn_update_dpp(0, __builtin_bit_cast(int, x),
                                        0x120 + N, 0xF, 0xF, true);
    return __builtin_bit_cast(float, r);
}

static __device__ __forceinline__ float exp2_fast(float x) {
#if __has_builtin(__builtin_amdgcn_exp2f)
    return __builtin_amdgcn_exp2f(x);
#else
    return exp2f(x);
#endif
}

// Linear-domain band-limited soft-DTW, two problems per wave (f, f+16; same b).
// Z = 2^S2 * exp(-D);  Z[i,j] = exp(-C[i,j]) * (Z[i-1,j] + Z[i,j-1] + Z[i-1,j-1])
//
// MEMORY-FREE MAIN LOOP: lane j at step d needs x[d-j], which lane j-1 held at
// step d-1 -> x flows right via the same wave_shr1 DPP as the DP recurrence.
// Only x[d] (wave-uniform) is injected at lane 0 each step, from an SGPR
// buffer filled by uniform scalar loads (32/chunk, double-buffered). No LDS,
// no per-lane loads, no lgkmcnt on the chain.
__global__ __launch_bounds__(64) void dtw_kernel(const float* __restrict__ x,
                                                 const float* __restrict__ protos,
                                                 float* __restrict__ out) {
    const int lane = threadIdx.x & 63;
    const int b    = blockIdx.x >> 4;            // 1024 blocks: 16 per b
    const int fA   = blockIdx.x & 15;
    const int fB   = fA + 16;

    const float* __restrict__ xr = x + b * T_LEN;   // wave-uniform row

    // -p*s for the fma form: ds = fma(xv, SQRT_LOG2E, pn) = (xv - p)*s
    const float pAn = -protos[fA * K_LEN + lane] * SQRT_LOG2E;
    const float pBn = -protos[fB * K_LEN + lane] * SQRT_LOG2E;
    const float jj  = (float)lane / 63.0f;
    const bool lane0 = (lane == 0);

    // exact fp32 band interval per column (same predicate as reference)
    int a0 = 0, b0 = T_LEN - 1;
    while (a0 < b0) { int m = (a0 + b0) >> 1;
        if ((float)m / 511.0f - jj >= -0.2f) b0 = m; else a0 = m + 1; }
    const int ilo = a0;
    a0 = 0; b0 = T_LEN - 1;
    while (a0 < b0) { int m = (a0 + b0 + 1) >> 1;
        if ((float)m / 511.0f - jj <= 0.2f) a0 = m; else b0 = m - 1; }
    const int ihi = a0;

    const unsigned range = (unsigned)(ihi - ilo);
    unsigned t = (unsigned)(-(lane + ilo));      // t = d - (lane+ilo)
    float xv    = 0.0f;                          // flowing x operand
    float prevA = 0.0f, prevB = 0.0f;
    float dgpA  = lane0 ? 1.0f : 0.0f;           // Z[-1,-1] = 1
    float dgpB  = dgpA;
    int   S2A = 0, S2B = 0;

#define STEP_BODY() do {                                        \
        float sel_ = (t <= range) ? 0.0f : -3.0e38f;            \
        ++t;                                                    \
        float dsA_ = __builtin_fmaf(xv, SQRT_LOG2E, pAn);       \
        float dsB_ = __builtin_fmaf(xv, SQRT_LOG2E, pBn);       \
        float wA_  = exp2_fast(__builtin_fmaf(dsA_, -dsA_, sel_)); \
        float wB_  = exp2_fast(__builtin_fmaf(dsB_, -dsB_, sel_)); \
        float lA_  = wave_shr1(prevA);                          \
        float lB_  = wave_shr1(prevB);                          \
        float aA_  = prevA + dgpA;                              \
        float aB_  = prevB + dgpB;                              \
        dgpA = lA_; dgpB = lB_;                                 \
        prevA = (aA_ + lA_) * wA_;                              \
        prevB = (aB_ + lB_) * wB_;                              \
    } while (0)

#define STEP_INJ(SK) do {                                       \
        float xs_ = wave_shr1(xv);                              \
        xv = lane0 ? (SK) : xs_;                                \
        STEP_BODY();                                            \
    } while (0)

#define STEP_TAIL() do {                                        \
        xv = wave_shr1(xv);   /* lane0 gets 0; its window is over */ \
        STEP_BODY();                                            \
    } while (0)

#define RENORM_HALF(PV, DG, S2) do {                                         \
        float m_ = PV;                                                       \
        m_ = fmaxf(m_, row_ror<8>(m_));                                      \
        m_ = fmaxf(m_, row_ror<4>(m_));                                      \
        m_ = fmaxf(m_, row_ror<2>(m_));                                      \
        m_ = fmaxf(m_, row_ror<1>(m_));                                      \
        int mi_ = __builtin_bit_cast(int, m_);                               \
        unsigned r0_ = (unsigned)__builtin_amdgcn_readlane(mi_, 0);          \
        unsigned r1_ = (unsigned)__builtin_amdgcn_readlane(mi_, 16);         \
        unsigned r2_ = (unsigned)__builtin_amdgcn_readlane(mi_, 32);         \
        unsigned r3_ = (unsigned)__builtin_amdgcn_readlane(mi_, 48);         \
        unsigned ra_ = r0_ > r1_ ? r0_ : r1_;                                \
        unsigned rb_ = r2_ > r3_ ? r2_ : r3_;                                \
        unsigned mx_ = ra_ > rb_ ? ra_ : rb_;                                \
        int e_  = (int)((mx_ >> 23) & 0xFF);                                 \
        int Me_ = 284 - e_;                                                  \
        Me_ = Me_ < 1 ? 1 : (Me_ > 254 ? 254 : Me_);                         \
        float M_ = __builtin_bit_cast(float, Me_ << 23);                     \
        S2 += Me_ - 127;                                                     \
        PV *= M_;                                                            \
        DG *= M_;                                                            \
    } while (0)

#define RENORM() do { RENORM_HALF(prevA, dgpA, S2A);                         \
                      RENORM_HALF(prevB, dgpB, S2B); } while (0)

    // scalar (wave-uniform) injection buffers, 32 values each, double-buffered
    float SA[32], SB[32];
#pragma unroll
    for (int k = 0; k < 32; ++k) SA[k] = xr[k];          // chunk 0

#pragma unroll 1
    for (int c = 0; c < 8; ++c) {
        const int o1 = (2 * c + 1) * 32;                 // chunk 2c+1
#pragma unroll
        for (int k = 0; k < 32; ++k) SB[k] = xr[o1 + k];
#pragma unroll
        for (int k = 0; k < 32; ++k) STEP_INJ(SA[k]);    // steps 64c .. 64c+31
        RENORM();
        const int o2 = (2 * c + 2 < 16) ? (2 * c + 2) * 32 : 15 * 32;  // clamp
#pragma unroll
        for (int k = 0; k < 32; ++k) SA[k] = xr[o2 + k];
#pragma unroll
        for (int k = 0; k < 32; ++k) STEP_INJ(SB[k]);    // steps 64c+32 .. 64c+63
        RENORM();
    }
    // tail: steps 512..574 (63 steps), no injection needed
#pragma unroll
    for (int k = 0; k < 32; ++k) STEP_TAIL();
    RENORM();
#pragma unroll
    for (int k = 0; k < 31; ++k) STEP_TAIL();

    if (lane == 63) {
        float DA = ((float)S2A - log2f(prevA)) * LN2;
        float DB = ((float)S2B - log2f(prevB)) * LN2;
        out[b * NFILT + fA] = DA * (1.0f / (float)T_LEN);
        out[b * NFILT + fB] = DB * (1.0f / (float)T_LEN);
    }
#undef STEP_BODY
#undef STEP_INJ
#undef STEP_TAIL
#undef RENORM_HALF
#undef RENORM
}

extern "C" void kernel_launch(void* const* d_in, const int* in_sizes, int n_in,
                              void* d_out, int out_size, void* d_ws, size_t ws_size,
                              hipStream_t stream) {
    const float* x      = (const float*)d_in[0];
    const float* protos = (const float*)d_in[1];
    float* out          = (float*)d_out;

    dim3 grid(NBATCH * 16);  // 1024 blocks x 1 wave = 1 wave/SIMD
    dim3 block(64);          // each wave: 2 problems (f, f+16), same b
    hipLaunchKernelGGL(dtw_kernel, grid, block, 0, stream, x, protos, out);
}